// Round 1
// baseline (123.428 us; speedup 1.0000x reference)
//
#include <hip/hip_runtime.h>
#include <math.h>

#define HH   1024
#define WW   1024
#define NIMG 32
#define COLS 32      // columns per block
#define Q    8       // H-chunks per column
#define CH   128     // rows per chunk (HH/Q)
#define NW   4       // bitmask words per chunk (CH/32)
#define NT   256     // threads per block (COLS*Q)
#define BIGD (1<<20)

// acc layout in d_ws: [0..7] double bce_sum, [8..15] u64 penalty_total, [16..19] u32 count
__global__ __launch_bounds__(NT) void dtl_main(const float* __restrict__ pred,
                                               const float* __restrict__ tgt,
                                               double* __restrict__ acc) {
    __shared__ unsigned tb_lds[Q * NW][COLS];   // target bits
    __shared__ unsigned pb_lds[Q * NW][COLS];   // pred>0 bits
    __shared__ int st_first[Q][COLS];           // first set-bit offset in chunk (-1 none)
    __shared__ int st_last[Q][COLS];            // last  set-bit offset in chunk (-1 none)
    __shared__ float    red_f[NT];
    __shared__ unsigned red_t[NT];
    __shared__ unsigned red_c[NT];

    const int tid = threadIdx.x;
    const int c   = tid & (COLS - 1);
    const int q   = tid / COLS;
    const int n   = blockIdx.x >> 5;            // WW/COLS == 32 groups per image
    const int wb  = (blockIdx.x & 31) * COLS;
    const int w   = wb + c;
    const int h0  = q * CH;
    const size_t base = ((size_t)n * HH + (size_t)h0) * WW + (size_t)w;
    const float* Pp = pred + base;
    const float* Tp = tgt + base;

    // ---------- Phase A: stream global once; BCE + pack bitmasks ----------
    float bce = 0.f;
    int first = -1, last = -1;

    for (int wi = 0; wi < NW; ++wi) {
        unsigned tm = 0u, pm = 0u;
#pragma unroll
        for (int b = 0; b < 32; ++b) {
            const int s = wi * 32 + b;
            const float p = Pp[(size_t)s * WW];
            const float t = Tp[(size_t)s * WW];
            // numerically-stable BCE-with-logits term
            bce += fmaxf(p, 0.f) - p * t + __logf(1.f + __expf(-fabsf(p)));
            const unsigned isT = (t != 0.f) ? 1u : 0u;
            const unsigned isP = (p > 0.f) ? 1u : 0u;
            tm |= isT << b;
            pm |= isP << b;
            if (isT) { if (first < 0) first = s; last = s; }
        }
        tb_lds[q * NW + wi][c] = tm;
        pb_lds[q * NW + wi][c] = pm;
    }
    st_first[q][c] = first;
    st_last[q][c]  = last;
    __syncthreads();

    // ---------- cross-chunk carries ----------
    // U = distance from row (h0-1) up to nearest target at-or-above it
    int U = BIGD;
    for (int k = q - 1; k >= 0; --k) {
        const int l = st_last[k][c];
        if (l >= 0) { U = (h0 - 1) - (k * CH + l); break; }
    }
    // absolute row of first target below this chunk (BIGD if none)
    int nxt_below = BIGD;
    for (int k = q + 1; k < Q; ++k) {
        const int fs = st_first[k][c];
        if (fs >= 0) { nxt_below = k * CH + fs; break; }
    }

    // ---------- Phase B: per-element distance from LDS bits only ----------
    int f = U;                                   // fwd dist at row h0-1
    int nxt = (first >= 0) ? (h0 + first) : nxt_below;  // next target row >= h
    unsigned tot = 0u, cnt = 0u;

    for (int wi = 0; wi < NW; ++wi) {
        const unsigned tw = tb_lds[q * NW + wi][c];
        const unsigned pw = pb_lds[q * NW + wi][c];
#pragma unroll
        for (int b = 0; b < 32; ++b) {
            const int h = h0 + wi * 32 + b;
            const int t = (int)((tw >> b) & 1u);
            f = t ? 0 : (f + 1);
            if (h > nxt) {                       // passed a target: advance lookahead
                unsigned m = tw & (0xFFFFFFFFu << b);
                int wj = wi;
                while (m == 0u && ++wj < NW) m = tb_lds[q * NW + wj][c];
                nxt = m ? (h0 + wj * 32 + (__ffs(m) - 1)) : nxt_below;
            }
            int d = nxt - h;                     // backward dist (0 on target rows)
            d = (f < d) ? f : d;
            d = (d < HH) ? d : HH;               // cap at H (no-target columns)
            const int pi = (int)((pw >> b) & 1u);
            if (pi && d > 0) { tot += (unsigned)d; cnt += 1u; }
        }
    }

    // ---------- block reduction ----------
    red_f[tid] = bce; red_t[tid] = tot; red_c[tid] = cnt;
    __syncthreads();
    for (int off = NT / 2; off > 0; off >>= 1) {
        if (tid < off) {
            red_f[tid] += red_f[tid + off];
            red_t[tid] += red_t[tid + off];
            red_c[tid] += red_c[tid + off];
        }
        __syncthreads();
    }
    if (tid == 0) {
        atomicAdd(acc, (double)red_f[0]);
        atomicAdd((unsigned long long*)(acc + 1), (unsigned long long)red_t[0]);
        atomicAdd((unsigned*)(acc + 2), red_c[0]);
    }
}

__global__ void dtl_final(const double* __restrict__ acc, float* __restrict__ out) {
    const double bce = acc[0] / (double)((size_t)NIMG * HH * WW);
    const unsigned long long tot = ((const unsigned long long*)acc)[1];
    const unsigned cnt = ((const unsigned*)acc)[4];  // byte offset 16
    double border = 0.0;
    if (tot != 0ull) {
        const unsigned cc = (cnt > 1u) ? cnt : 1u;
        border = sqrt((double)tot / (double)cc);
    }
    out[0] = (float)(bce + border);
}

extern "C" void kernel_launch(void* const* d_in, const int* in_sizes, int n_in,
                              void* d_out, int out_size, void* d_ws, size_t ws_size,
                              hipStream_t stream) {
    const float* pred = (const float*)d_in[0];
    const float* tgt  = (const float*)d_in[1];
    float* out = (float*)d_out;

    hipMemsetAsync(d_ws, 0, 32, stream);  // zero accumulators (capturable)

    const int grid = NIMG * (WW / COLS);  // 32 * 32 = 1024 blocks
    dtl_main<<<grid, NT, 0, stream>>>(pred, tgt, (double*)d_ws);
    dtl_final<<<1, 1, 0, stream>>>((const double*)d_ws, out);
}

// Round 2
// 105.043 us; speedup vs baseline: 1.1750x; 1.1750x over previous
//
#include <hip/hip_runtime.h>
#include <math.h>

#define HH   1024
#define WW   1024
#define NIMG 32
#define COLS 32          // columns per block
#define NT   512         // threads per block (8 waves)
#define NWAVES 8
#define QB   16          // H-chunks in phase B (per column)
#define CHB  64          // rows per phase-B chunk
#define BIGD (1<<20)

// acc layout in d_ws: [0] double bce_sum, [1] u64 penalty_total, byte16 u32 count
__global__ __launch_bounds__(NT, 4) void dtl_main(const float* __restrict__ pred,
                                                  const float* __restrict__ tgt,
                                                  double* __restrict__ acc) {
    __shared__ unsigned long long tb64[HH / 2];   // bit (c + 32*(h&1)) of word h/2
    __shared__ unsigned long long pb64[HH / 2];
    __shared__ int st_first[QB][COLS];
    __shared__ int st_last[QB][COLS];
    __shared__ float    red_f[NT];
    __shared__ unsigned red_t[NT];
    __shared__ unsigned red_c[NT];

    const int tid  = threadIdx.x;
    const int lane = tid & 63;
    const int wv   = tid >> 6;                    // 0..7
    const int n    = blockIdx.x >> 5;             // image
    const int wb   = (blockIdx.x & 31) * COLS;    // column base

    // ---------------- Phase A: coalesced stream + ballot bit-pack ----------
    // wave wv owns rows [wv*128, wv*128+128); lane covers (h&1, c)
    const int hh = wv * 128 + (lane >> 5);
    const int w  = wb + (lane & 31);
    const float* Pp = pred + ((size_t)n * HH + hh) * WW + w;
    const float* Tp = tgt  + ((size_t)n * HH + hh) * WW + w;

    float bce = 0.f;
    const int widx = wv * 64;                     // word index base for this wave

#pragma unroll 1
    for (int i = 0; i < 64; i += 4) {
        // 8 independent loads issued before any use
        const float p0 = Pp[0 * 2048], p1 = Pp[1 * 2048], p2 = Pp[2 * 2048], p3 = Pp[3 * 2048];
        const float t0 = Tp[0 * 2048], t1 = Tp[1 * 2048], t2 = Tp[2 * 2048], t3 = Tp[3 * 2048];
        Pp += 4 * 2048; Tp += 4 * 2048;

        bce += fmaxf(p0, 0.f) - p0 * t0 + __logf(1.f + __expf(-fabsf(p0)));
        bce += fmaxf(p1, 0.f) - p1 * t1 + __logf(1.f + __expf(-fabsf(p1)));
        bce += fmaxf(p2, 0.f) - p2 * t2 + __logf(1.f + __expf(-fabsf(p2)));
        bce += fmaxf(p3, 0.f) - p3 * t3 + __logf(1.f + __expf(-fabsf(p3)));

        const unsigned long long bt0 = __ballot(t0 != 0.f), bp0 = __ballot(p0 > 0.f);
        const unsigned long long bt1 = __ballot(t1 != 0.f), bp1 = __ballot(p1 > 0.f);
        const unsigned long long bt2 = __ballot(t2 != 0.f), bp2 = __ballot(p2 > 0.f);
        const unsigned long long bt3 = __ballot(t3 != 0.f), bp3 = __ballot(p3 > 0.f);
        if (lane == 0) {
            tb64[widx + i + 0] = bt0;  pb64[widx + i + 0] = bp0;
            tb64[widx + i + 1] = bt1;  pb64[widx + i + 1] = bp1;
            tb64[widx + i + 2] = bt2;  pb64[widx + i + 2] = bp2;
            tb64[widx + i + 3] = bt3;  pb64[widx + i + 3] = bp3;
        }
    }
    __syncthreads();

    // ---------------- Phase B: distances from LDS bits ---------------------
    const int c  = tid & (COLS - 1);
    const int q  = tid >> 5;                      // 0..15 chunk of 64 rows
    const int h0 = q * CHB;

    // compact this column-chunk into one u64 per mask (broadcast LDS reads)
    unsigned long long tw = 0ull, pw = 0ull;
#pragma unroll 8
    for (int j = 0; j < 32; ++j) {
        const unsigned long long wt = tb64[q * 32 + j];
        const unsigned long long wp = pb64[q * 32 + j];
        tw |= (((wt >> c) & 1ull) << (2 * j)) | (((wt >> (c + 32)) & 1ull) << (2 * j + 1));
        pw |= (((wp >> c) & 1ull) << (2 * j)) | (((wp >> (c + 32)) & 1ull) << (2 * j + 1));
    }
    const int first = tw ? __builtin_ctzll(tw) : -1;
    const int last  = tw ? (63 - __builtin_clzll(tw)) : -1;
    st_first[q][c] = first;
    st_last[q][c]  = last;
    __syncthreads();

    // cross-chunk carries
    int U = BIGD;                                 // dist from row h0-1 up to nearest target
    for (int k = q - 1; k >= 0; --k) {
        const int l2 = st_last[k][c];
        if (l2 >= 0) { U = (h0 - 1) - (k * CHB + l2); break; }
    }
    int nxt_below = BIGD;                         // first target row below this chunk
    for (int k = q + 1; k < QB; ++k) {
        const int fs = st_first[k][c];
        if (fs >= 0) { nxt_below = k * CHB + fs; break; }
    }

    int f   = U;                                  // fwd dist at row h0-1
    int nxt = (first >= 0) ? (h0 + first) : nxt_below;
    unsigned tot = 0u, cnt = 0u;

#pragma unroll 4
    for (int b = 0; b < 64; ++b) {
        const int h = h0 + b;
        const int t = (int)((tw >> b) & 1ull);
        f = t ? 0 : (f + 1);
        if (h > nxt) {                            // passed a target: find next set bit >= b
            const unsigned long long m = tw & (~0ull << b);
            nxt = m ? (h0 + __builtin_ctzll(m)) : nxt_below;
        }
        int d = nxt - h;
        d = (f < d) ? f : d;
        d = (d < HH) ? d : HH;                    // cap (no-target columns)
        if (((pw >> b) & 1ull) && d > 0) { tot += (unsigned)d; cnt += 1u; }
    }

    // ---------------- block reduction --------------------------------------
    red_f[tid] = bce; red_t[tid] = tot; red_c[tid] = cnt;
    __syncthreads();
    for (int off = NT / 2; off > 0; off >>= 1) {
        if (tid < off) {
            red_f[tid] += red_f[tid + off];
            red_t[tid] += red_t[tid + off];
            red_c[tid] += red_c[tid + off];
        }
        __syncthreads();
    }
    if (tid == 0) {
        atomicAdd(acc, (double)red_f[0]);
        atomicAdd((unsigned long long*)(acc + 1), (unsigned long long)red_t[0]);
        atomicAdd((unsigned*)(acc + 2), red_c[0]);
    }
}

__global__ void dtl_final(const double* __restrict__ acc, float* __restrict__ out) {
    const double bce = acc[0] / (double)((size_t)NIMG * HH * WW);
    const unsigned long long tot = ((const unsigned long long*)acc)[1];
    const unsigned cnt = ((const unsigned*)acc)[4];  // byte offset 16
    double border = 0.0;
    if (tot != 0ull) {
        const unsigned cc = (cnt > 1u) ? cnt : 1u;
        border = sqrt((double)tot / (double)cc);
    }
    out[0] = (float)(bce + border);
}

extern "C" void kernel_launch(void* const* d_in, const int* in_sizes, int n_in,
                              void* d_out, int out_size, void* d_ws, size_t ws_size,
                              hipStream_t stream) {
    const float* pred = (const float*)d_in[0];
    const float* tgt  = (const float*)d_in[1];
    float* out = (float*)d_out;

    hipMemsetAsync(d_ws, 0, 32, stream);  // zero accumulators (capturable)

    const int grid = NIMG * (WW / COLS);  // 32 * 32 = 1024 blocks
    dtl_main<<<grid, NT, 0, stream>>>(pred, tgt, (double*)d_ws);
    dtl_final<<<1, 1, 0, stream>>>((const double*)d_ws, out);
}